// Round 5
// baseline (139.303 us; speedup 1.0000x reference)
//
#include <hip/hip_runtime.h>

#define BLK 128
#define SEG 4            // candidate segments per row: 4096 blocks, 256 cand/block
#define CAND 256         // candidates per block
#define NJ 8

// Phase-1 kernel: block (i, seg) tests 256 candidate neighbors of row i,
// compacts actives (dist<0.5) into LDS, runs conv1->relu->conv2 (thread t owns
// conv2 channel t, 64 weights in VGPRs), and atomicMax's the per-channel
// partial max into pooled[i*128+t] (f32 bits as int: all values >= 0, and the
// 0xAA ws poison is a negative int so it always loses).
__global__ __launch_bounds__(BLK) void pool_partial_kernel(
    const float* __restrict__ s,
    const float* __restrict__ w1g, const float* __restrict__ b1g,
    const float* __restrict__ w2g, const float* __restrict__ b2g,
    int* __restrict__ pooled)
{
    __shared__ float w1[320];
    __shared__ float b1[64];
    __shared__ float4 acts[CAND];     // staged s rows of active neighbors
    __shared__ int actj[CAND];
    __shared__ float h1buf[NJ][64];
    __shared__ int cnt;

    const int tid = threadIdx.x;
    const int i   = blockIdx.x >> 2;       // row
    const int seg = blockIdx.x & 3;        // candidate segment

    if (tid == 0) cnt = 0;
    for (int q = tid; q < 320; q += BLK) w1[q] = w1g[q];
    if (tid < 64) b1[tid] = b1g[tid];

    // conv2 row o=tid -> 64 f32 in registers (L1-resident after first block/CU)
    float w2r[64];
    {
        const float4* wrow = (const float4*)(w2g + tid * 64);
        #pragma unroll
        for (int q = 0; q < 16; ++q) {
            float4 u = wrow[q];
            w2r[4*q+0] = u.x; w2r[4*q+1] = u.y;
            w2r[4*q+2] = u.z; w2r[4*q+3] = u.w;
        }
    }
    const float b2r = b2g[tid];

    const float4 si = ((const float4*)s)[i];   // wave-uniform broadcast load
    __syncthreads();

    // test 2 candidates per thread, compact actives into LDS
    const int j0 = seg * CAND;
    #pragma unroll
    for (int p = 0; p < 2; ++p) {
        const int j = j0 + p * BLK + tid;
        float4 sj = ((const float4*)s)[j];
        float dx = si.x - sj.x, dy = si.y - sj.y;
        if (dx * dx + dy * dy < 0.25f) {
            int slot = atomicAdd(&cnt, 1);
            acts[slot] = sj;
            actj[slot] = j;
        }
    }
    __syncthreads();
    const int n_act = cnt;   // avg ~15

    float m = 0.0f;          // conv2 relu folded into max with 0
    for (int base = 0; base < n_act; base += NJ) {
        const int nj = min(NJ, n_act - base);
        // conv1: 64*nj items over 128 threads
        for (int w = tid; w < (nj << 6); w += BLK) {
            const int c = w & 63, slot = w >> 6;
            const float4 sj = acts[base + slot];
            const float x0 = si.x - sj.x, x1 = si.y - sj.y;
            const float x2 = si.z - sj.z, x3 = si.w - sj.w;
            const float x4 = (actj[base + slot] == i) ? 1.0f : 0.0f;
            const float* wr = &w1[c * 5];
            float h = b1[c];
            h = fmaf(wr[0], x0, h);
            h = fmaf(wr[1], x1, h);
            h = fmaf(wr[2], x2, h);
            h = fmaf(wr[3], x3, h);
            h = fmaf(wr[4], x4, h);
            h1buf[slot][c] = fmaxf(h, 0.0f);
        }
        __syncthreads();
        // conv2: broadcast ds_read_b128 of h1, 64 reg-weight FMAs per neighbor
        for (int slot = 0; slot < nj; ++slot) {
            float acc = b2r;
            const float4* hv = (const float4*)(&h1buf[slot][0]);
            #pragma unroll
            for (int q = 0; q < 16; ++q) {
                float4 h4 = hv[q];
                acc = fmaf(w2r[4*q+0], h4.x, acc);
                acc = fmaf(w2r[4*q+1], h4.y, acc);
                acc = fmaf(w2r[4*q+2], h4.z, acc);
                acc = fmaf(w2r[4*q+3], h4.w, acc);
            }
            m = fmaxf(m, acc);
        }
        __syncthreads();
    }

    // non-negative f32 bits compare correctly as signed int; poison loses
    atomicMax(&pooled[i * 128 + tid], __float_as_int(m));
}

// Phase-2 kernel: one block per row — validated round-4 MLP head logic.
__global__ __launch_bounds__(BLK) void head_kernel(
    const float* __restrict__ s,    const float* __restrict__ g,
    const float* __restrict__ fc1w, const float* __restrict__ fc1b,
    const float* __restrict__ fc2w, const float* __restrict__ fc2b,
    const float* __restrict__ fc3w, const float* __restrict__ fc3b,
    const float* __restrict__ fc4w, const float* __restrict__ fc4b,
    const float* __restrict__ pooled,
    float2* __restrict__ out)
{
    __shared__ float feat[132];
    __shared__ float z1[64];
    __shared__ float z2[128];
    __shared__ float z3[64];
    __shared__ float kk[4];

    const int tid = threadIdx.x;
    const int i = blockIdx.x;

    const float4 si = ((const float4*)s)[i];

    feat[tid] = pooled[i * 128 + tid];
    if (tid == 0) {
        float2 gi = ((const float2*)g)[i];
        feat[128] = si.x - gi.x;
        feat[129] = si.y - gi.y;
        feat[130] = si.z;
        feat[131] = si.w;
    }
    __syncthreads();

    // fc1: 132 -> 64 (threads 0..63)
    if (tid < 64) {
        float acc = fc1b[tid];
        const float4* wv = (const float4*)(fc1w + tid * 132);
        #pragma unroll
        for (int q = 0; q < 33; ++q) {
            float4 u = wv[q];
            int k = q * 4;
            acc = fmaf(u.x, feat[k+0], acc);
            acc = fmaf(u.y, feat[k+1], acc);
            acc = fmaf(u.z, feat[k+2], acc);
            acc = fmaf(u.w, feat[k+3], acc);
        }
        z1[tid] = fmaxf(acc, 0.0f);
    }
    __syncthreads();

    // fc2: 64 -> 128 (all 128 threads)
    {
        float acc = fc2b[tid];
        const float4* wv = (const float4*)(fc2w + tid * 64);
        #pragma unroll
        for (int q = 0; q < 16; ++q) {
            float4 u = wv[q];
            int k = q * 4;
            acc = fmaf(u.x, z1[k+0], acc);
            acc = fmaf(u.y, z1[k+1], acc);
            acc = fmaf(u.z, z1[k+2], acc);
            acc = fmaf(u.w, z1[k+3], acc);
        }
        z2[tid] = fmaxf(acc, 0.0f);
    }
    __syncthreads();

    // fc3: 128 -> 64 (threads 0..63)
    if (tid < 64) {
        float acc = fc3b[tid];
        const float4* wv = (const float4*)(fc3w + tid * 128);
        #pragma unroll
        for (int q = 0; q < 32; ++q) {
            float4 u = wv[q];
            int k = q * 4;
            acc = fmaf(u.x, z2[k+0], acc);
            acc = fmaf(u.y, z2[k+1], acc);
            acc = fmaf(u.z, z2[k+2], acc);
            acc = fmaf(u.w, z2[k+3], acc);
        }
        z3[tid] = fmaxf(acc, 0.0f);
    }
    __syncthreads();

    // fc4 (64->4) + sigmoid gain
    if (tid < 4) {
        float acc = fc4b[tid];
        const float4* wv = (const float4*)(fc4w + tid * 64);
        #pragma unroll
        for (int q = 0; q < 16; ++q) {
            float4 u = wv[q];
            int k = q * 4;
            acc = fmaf(u.x, z3[k+0], acc);
            acc = fmaf(u.y, z3[k+1], acc);
            acc = fmaf(u.z, z3[k+2], acc);
            acc = fmaf(u.w, z3[k+3], acc);
        }
        kk[tid] = 2.0f / (1.0f + expf(-acc)) - 1.0f;   // 2*sigmoid - 1
    }
    __syncthreads();

    if (tid == 0) {
        float sgx = feat[128], sgy = feat[129];
        float vx  = feat[130], vy  = feat[131];
        float ax = -(kk[0] * sgx + kk[1] * vx);
        float ay = -(kk[2] * sgy + kk[3] * vy);
        out[i] = make_float2(ax, ay);
    }
}

extern "C" void kernel_launch(void* const* d_in, const int* in_sizes, int n_in,
                              void* d_out, int out_size, void* d_ws, size_t ws_size,
                              hipStream_t stream) {
    const float* s    = (const float*)d_in[0];
    const float* g    = (const float*)d_in[1];
    const float* c1w  = (const float*)d_in[2];
    const float* c1b  = (const float*)d_in[3];
    const float* c2w  = (const float*)d_in[4];
    const float* c2b  = (const float*)d_in[5];
    const float* fc1w = (const float*)d_in[6];
    const float* fc1b = (const float*)d_in[7];
    const float* fc2w = (const float*)d_in[8];
    const float* fc2b = (const float*)d_in[9];
    const float* fc3w = (const float*)d_in[10];
    const float* fc3b = (const float*)d_in[11];
    const float* fc4w = (const float*)d_in[12];
    const float* fc4b = (const float*)d_in[13];

    int*   pooled_i = (int*)d_ws;            // 1024*128 f32-as-int = 512 KB
    float* pooled_f = (float*)d_ws;
    float2* out = (float2*)d_out;

    pool_partial_kernel<<<1024 * SEG, BLK, 0, stream>>>(
        s, c1w, c1b, c2w, c2b, pooled_i);
    head_kernel<<<1024, BLK, 0, stream>>>(
        s, g, fc1w, fc1b, fc2w, fc2b, fc3w, fc3b, fc4w, fc4b, pooled_f, out);
}

// Round 6
// 95.778 us; speedup vs baseline: 1.4544x; 1.4544x over previous
//
#include <hip/hip_runtime.h>

typedef unsigned int u32;
typedef unsigned short u16;
typedef _Float16 f16;
typedef f16 f16x8 __attribute__((ext_vector_type(8)));
typedef float f32x4 __attribute__((ext_vector_type(4)));

#define NTH 256
#define SH1 72   // h1buf row stride in f16 (144 B: breaks 128B bank wrap on A-frag reads)

// Fully fused, one 256-thread block (4 waves) per row i.
//  Phase 1: scan all 1024 candidates (coalesced float4), compact actives
//           (dist<0.5) into LDS.
//  Phase 2: per 16-pair group: conv1 (f32 VALU) -> h1 packed f16 in LDS ->
//           conv2 via v_mfma_f32_16x16x32_f16 (wave w owns channels
//           [32w,32w+32) as two 16-wide N-tiles; w2 B-fragments live in 16
//           VGPRs, loaded once) -> masked max epilogue in C-layout ->
//           shfl reduce. Round-5 post-mortem: the old VALU conv2 was
//           LDS-return-pipe bound (16 broadcast ds_read_b128/pair/wave,
//           ~384 cyc/pair); MFMA needs 2 fragment reads per group per wave.
//  Phase 3: MLP head + gain epilogue in-block (feat = pooled in LDS).
__global__ __launch_bounds__(NTH) void NetworkAction_86131274154571_kernel(
    const float* __restrict__ s,    const float* __restrict__ g,
    const float* __restrict__ w1g,  const float* __restrict__ b1g,
    const float* __restrict__ w2g,  const float* __restrict__ b2g,
    const float* __restrict__ fc1w, const float* __restrict__ fc1b,
    const float* __restrict__ fc2w, const float* __restrict__ fc2b,
    const float* __restrict__ fc3w, const float* __restrict__ fc3b,
    const float* __restrict__ fc4w, const float* __restrict__ fc4b,
    float2* __restrict__ out)
{
    __shared__ float4 acts[1024];     // s rows of active neighbors
    __shared__ int    actj[1024];
    __shared__ f16    h1buf[16][SH1]; // one 16-pair group of conv1 outputs
    __shared__ float  w1s[320];
    __shared__ float  b1s[64];
    __shared__ float  feat[132];      // [0..127] = pooled, [128..131] = sg|v
    __shared__ float  z1[64];
    __shared__ float  z2[128];
    __shared__ float  z3[64];
    __shared__ float  kk[4];
    __shared__ int    cnt;

    const int tid  = threadIdx.x;
    const int lane = tid & 63;
    const int wave = tid >> 6;
    const int i    = blockIdx.x;

    if (tid == 0) cnt = 0;
    for (int q = tid; q < 320; q += NTH) w1s[q] = w1g[q];
    if (tid < 64) b1s[tid] = b1g[tid];
    __syncthreads();   // cnt=0 + w1/b1 visible

    const float4 si = ((const float4*)s)[i];   // uniform

    // ---- Phase 1: scan + compact ----
    #pragma unroll
    for (int p = 0; p < 4; ++p) {
        const int j = p * NTH + tid;           // coalesced
        float4 sj = ((const float4*)s)[j];
        float dx = si.x - sj.x, dy = si.y - sj.y;
        if (dx * dx + dy * dy < 0.25f) {
            int slot = atomicAdd(&cnt, 1);
            acts[slot] = sj;
            actj[slot] = j;
        }
    }
    __syncthreads();
    const int n_act = cnt;                     // >=1 (diagonal)

    // ---- w2 B-fragments (once per block): wave owns channels 32w..32w+31 ----
    // B[k][n] = w2[n][k]; lane: n = n0 + (lane&15), k = (lane>>4)*8 + j
    const int n_base = wave * 32;
    const int ncol   = lane & 15;
    const int kq     = lane >> 4;              // 0..3
    f16x8 bfrag[2][2];                          // [tile][kstep]
    float b2r[2];
    #pragma unroll
    for (int tile = 0; tile < 2; ++tile) {
        const int n = n_base + tile * 16 + ncol;
        b2r[tile] = b2g[n];
        #pragma unroll
        for (int t = 0; t < 2; ++t) {
            const float* wp = w2g + n * 64 + t * 32 + kq * 8;
            float4 lo = ((const float4*)wp)[0];
            float4 hi = ((const float4*)wp)[1];
            f16x8 b;
            b[0] = (f16)lo.x; b[1] = (f16)lo.y; b[2] = (f16)lo.z; b[3] = (f16)lo.w;
            b[4] = (f16)hi.x; b[5] = (f16)hi.y; b[6] = (f16)hi.z; b[7] = (f16)hi.w;
            bfrag[tile][t] = b;
        }
    }

    float mtile[2] = {0.0f, 0.0f};   // running max per N-tile (relu folded)

    // ---- Phase 2: groups of 16 pairs ----
    for (int gbase = 0; gbase < n_act; gbase += 16) {
        // conv1: 16 pairs x 32 f16-pairs = 512 items over 256 threads
        #pragma unroll
        for (int it = 0; it < 2; ++it) {
            const int idx = it * NTH + tid;
            const int p = idx >> 5, c2 = idx & 31;
            if (gbase + p < n_act) {
                const float4 sj = acts[gbase + p];
                const float x0 = si.x - sj.x, x1 = si.y - sj.y;
                const float x2 = si.z - sj.z, x3 = si.w - sj.w;
                const float x4 = (actj[gbase + p] == i) ? 1.0f : 0.0f;
                const int c = c2 * 2;
                const float* wa = &w1s[c * 5];
                float ha = b1s[c];
                ha = fmaf(wa[0], x0, ha); ha = fmaf(wa[1], x1, ha);
                ha = fmaf(wa[2], x2, ha); ha = fmaf(wa[3], x3, ha);
                ha = fmaf(wa[4], x4, ha);
                const float* wb = &w1s[c * 5 + 5];
                float hb = b1s[c + 1];
                hb = fmaf(wb[0], x0, hb); hb = fmaf(wb[1], x1, hb);
                hb = fmaf(wb[2], x2, hb); hb = fmaf(wb[3], x3, hb);
                hb = fmaf(wb[4], x4, hb);
                f16 fa = (f16)fmaxf(ha, 0.0f);
                f16 fb = (f16)fmaxf(hb, 0.0f);
                u32 pk = (u32)__builtin_bit_cast(u16, fa) |
                         ((u32)__builtin_bit_cast(u16, fb) << 16);
                *(u32*)&h1buf[p][c2 * 2] = pk;   // 4B-aligned, 2-way banks (free)
            }
        }
        __syncthreads();

        // conv2 MFMA: A-frags shared by both tiles
        f16x8 afr[2];
        #pragma unroll
        for (int t = 0; t < 2; ++t)
            afr[t] = *(const f16x8*)&h1buf[ncol][t * 32 + kq * 8];  // 16B-aligned

        #pragma unroll
        for (int tile = 0; tile < 2; ++tile) {
            f32x4 acc = {0.0f, 0.0f, 0.0f, 0.0f};
            acc = __builtin_amdgcn_mfma_f32_16x16x32_f16(afr[0], bfrag[tile][0], acc, 0, 0, 0);
            acc = __builtin_amdgcn_mfma_f32_16x16x32_f16(afr[1], bfrag[tile][1], acc, 0, 0, 0);
            // D: pair row = kq*4 + r, channel col = ncol; mask pad rows
            #pragma unroll
            for (int r = 0; r < 4; ++r) {
                const bool valid = (gbase + kq * 4 + r) < n_act;
                const float v = acc[r] + b2r[tile];
                mtile[tile] = valid ? fmaxf(mtile[tile], v) : mtile[tile];
            }
        }
        __syncthreads();   // h1buf reused next group
    }

    // reduce across the 4 row-quads holding the same channel column
    #pragma unroll
    for (int tile = 0; tile < 2; ++tile) {
        float m = mtile[tile];
        m = fmaxf(m, __shfl_xor(m, 16));
        m = fmaxf(m, __shfl_xor(m, 32));
        if (lane < 16) feat[n_base + tile * 16 + lane] = m;
    }
    if (tid == 0) {
        float2 gi = ((const float2*)g)[i];
        feat[128] = si.x - gi.x;
        feat[129] = si.y - gi.y;
        feat[130] = si.z;
        feat[131] = si.w;
    }
    __syncthreads();

    // ---- Phase 3: MLP head (validated round-4 logic) ----
    if (tid < 64) {
        float acc = fc1b[tid];
        const float4* wv = (const float4*)(fc1w + tid * 132);
        #pragma unroll
        for (int q = 0; q < 33; ++q) {
            float4 u = wv[q];
            int k = q * 4;
            acc = fmaf(u.x, feat[k+0], acc);
            acc = fmaf(u.y, feat[k+1], acc);
            acc = fmaf(u.z, feat[k+2], acc);
            acc = fmaf(u.w, feat[k+3], acc);
        }
        z1[tid] = fmaxf(acc, 0.0f);
    }
    __syncthreads();

    if (tid < 128) {
        float acc = fc2b[tid];
        const float4* wv = (const float4*)(fc2w + tid * 64);
        #pragma unroll
        for (int q = 0; q < 16; ++q) {
            float4 u = wv[q];
            int k = q * 4;
            acc = fmaf(u.x, z1[k+0], acc);
            acc = fmaf(u.y, z1[k+1], acc);
            acc = fmaf(u.z, z1[k+2], acc);
            acc = fmaf(u.w, z1[k+3], acc);
        }
        z2[tid] = fmaxf(acc, 0.0f);
    }
    __syncthreads();

    if (tid < 64) {
        float acc = fc3b[tid];
        const float4* wv = (const float4*)(fc3w + tid * 128);
        #pragma unroll
        for (int q = 0; q < 32; ++q) {
            float4 u = wv[q];
            int k = q * 4;
            acc = fmaf(u.x, z2[k+0], acc);
            acc = fmaf(u.y, z2[k+1], acc);
            acc = fmaf(u.z, z2[k+2], acc);
            acc = fmaf(u.w, z2[k+3], acc);
        }
        z3[tid] = fmaxf(acc, 0.0f);
    }
    __syncthreads();

    if (tid < 4) {
        float acc = fc4b[tid];
        const float4* wv = (const float4*)(fc4w + tid * 64);
        #pragma unroll
        for (int q = 0; q < 16; ++q) {
            float4 u = wv[q];
            int k = q * 4;
            acc = fmaf(u.x, z3[k+0], acc);
            acc = fmaf(u.y, z3[k+1], acc);
            acc = fmaf(u.z, z3[k+2], acc);
            acc = fmaf(u.w, z3[k+3], acc);
        }
        kk[tid] = 2.0f / (1.0f + expf(-acc)) - 1.0f;
    }
    __syncthreads();

    if (tid == 0) {
        float ax = -(kk[0] * feat[128] + kk[1] * feat[130]);
        float ay = -(kk[2] * feat[129] + kk[3] * feat[131]);
        out[i] = make_float2(ax, ay);
    }
}

extern "C" void kernel_launch(void* const* d_in, const int* in_sizes, int n_in,
                              void* d_out, int out_size, void* d_ws, size_t ws_size,
                              hipStream_t stream) {
    const float* s    = (const float*)d_in[0];
    const float* g    = (const float*)d_in[1];
    const float* c1w  = (const float*)d_in[2];
    const float* c1b  = (const float*)d_in[3];
    const float* c2w  = (const float*)d_in[4];
    const float* c2b  = (const float*)d_in[5];
    const float* fc1w = (const float*)d_in[6];
    const float* fc1b = (const float*)d_in[7];
    const float* fc2w = (const float*)d_in[8];
    const float* fc2b = (const float*)d_in[9];
    const float* fc3w = (const float*)d_in[10];
    const float* fc3b = (const float*)d_in[11];
    const float* fc4w = (const float*)d_in[12];
    const float* fc4b = (const float*)d_in[13];

    float2* out = (float2*)d_out;

    NetworkAction_86131274154571_kernel<<<1024, NTH, 0, stream>>>(
        s, g, c1w, c1b, c2w, c2b, fc1w, fc1b, fc2w, fc2b,
        fc3w, fc3b, fc4w, fc4b, out);
}